// Round 6
// baseline (89.190 us; speedup 1.0000x reference)
//
#include <hip/hip_runtime.h>
#include <math.h>

// KANLinear forward, MI355X.
// out[b,i,o] = silu( (x@W)[b,o] + sum_k basis[b,i,k] * sw[i,o,k] )
// b=1024, i=256, o=256, k=7. Output 268MB f32 -> write-bound (~39us @ 6.9TB/s fill rate).
// R6 experiment: per-wave LINEAR write streams. Wave owns 4 b-streams over 32
// consecutive i -> 32KB contiguous runs per stream (vs 256KB-strided 1KB chunks).

#define NF 256

typedef float f32x4 __attribute__((ext_vector_type(4)));

__device__ __forceinline__ float silu_f(float z) {
    float e = __expf(-z);
    return z * __builtin_amdgcn_rcpf(1.0f + e);
}

// ---------------- Kernel 1: base = x @ W  (1024x256 @ 256x256) ----------------
__global__ __launch_bounds__(256) void base_gemm(const float* __restrict__ x,
                                                 const float* __restrict__ W,
                                                 float* __restrict__ base) {
    __shared__ float xs[4][NF];
    const int b0 = blockIdx.x * 4;
    const int t = threadIdx.x;
    {
        const int row = t >> 6;
        const int c4 = (t & 63) * 4;
        *reinterpret_cast<f32x4*>(&xs[row][c4]) =
            *reinterpret_cast<const f32x4*>(&x[(size_t)(b0 + row) * NF + c4]);
    }
    __syncthreads();
    float acc0 = 0.f, acc1 = 0.f, acc2 = 0.f, acc3 = 0.f;
#pragma unroll 8
    for (int k = 0; k < NF; ++k) {
        float w = W[k * NF + t];
        acc0 += xs[0][k] * w;
        acc1 += xs[1][k] * w;
        acc2 += xs[2][k] * w;
        acc3 += xs[3][k] * w;
    }
    base[(size_t)(b0 + 0) * NF + t] = acc0;
    base[(size_t)(b0 + 1) * NF + t] = acc1;
    base[(size_t)(b0 + 2) * NF + t] = acc2;
    base[(size_t)(b0 + 3) * NF + t] = acc3;
}

// ---------------- Kernel 2: fused basis + spline einsum + silu ----------------
// grid: (2 i-halves, 256 b-quads); 256 threads = 4 waves.
// Block: 4 b-rows x 128 i. Wave w: i in [i_base + w*32, +32), all 4 b-rows.
__global__ __launch_bounds__(256) void kan_main(const float* __restrict__ x,
                                                const float* __restrict__ sw,
                                                const float* __restrict__ grid,
                                                const float* __restrict__ base,
                                                float* __restrict__ out) {
    const int i_base = blockIdx.x * 128;
    const int b0 = blockIdx.y * 4;
    const int tid = threadIdx.x;

    __shared__ float bas[4][128][8];   // 16 KB [bb][i_loc][k]
    __shared__ float base_s[4][NF];    // 4 KB

    // ---- base rows -> LDS (256 f32x4 over 256 threads) ----
    {
        const int row = tid >> 6;
        const int c4 = (tid & 63) * 4;
        *reinterpret_cast<f32x4*>(&base_s[row][c4]) =
            *reinterpret_cast<const f32x4*>(&base[(size_t)(b0 + row) * NF + c4]);
    }

    // ---- basis: 512 (bb,i) pairs, 2 per thread (same i, bb and bb+2) ----
    {
        const int il = tid & 127;
        const int bbh = tid >> 7;  // 0/1
        const int i = i_base + il;
        const float g0 = grid[0 * NF + i];
        const float g1 = grid[1 * NF + i];
        const float g2 = grid[2 * NF + i];
        const float g3 = grid[3 * NF + i];
        const float g4 = grid[4 * NF + i];
        const float L = 2.f * g0 - g3;
        const float R = 2.f * g4 - g1;
        const float eg[11] = {L, L, L, g0, g1, g2, g3, g4, R, R, R};

#pragma unroll
        for (int rep = 0; rep < 2; ++rep) {
            const int bb = bbh + 2 * rep;
            const float xv = x[(size_t)(b0 + bb) * NF + i];

            float B0[10];
#pragma unroll
            for (int t = 0; t < 10; ++t)
                B0[t] = (xv >= eg[t] && xv < eg[t + 1]) ? 1.f : 0.f;
            float B1[9];
#pragma unroll
            for (int t = 0; t < 9; ++t) {
                const float dl = eg[t + 1] - eg[t];
                const float dr = eg[t + 2] - eg[t + 1];
                const float lt = (dl != 0.f) ? (xv - eg[t]) / dl : 0.f;
                const float rt = (dr != 0.f) ? (eg[t + 2] - xv) / dr : 0.f;
                B1[t] = lt * B0[t] + rt * B0[t + 1];
            }
            float B2[8];
#pragma unroll
            for (int t = 0; t < 8; ++t) {
                const float dl = eg[t + 2] - eg[t];
                const float dr = eg[t + 3] - eg[t + 1];
                const float lt = (dl != 0.f) ? (xv - eg[t]) / dl : 0.f;
                const float rt = (dr != 0.f) ? (eg[t + 3] - xv) / dr : 0.f;
                B2[t] = lt * B1[t] + rt * B1[t + 1];
            }
#pragma unroll
            for (int k = 0; k < 7; ++k) bas[bb][il][k] = B2[k];
            bas[bb][il][7] = 0.f;
        }
    }
    __syncthreads();

    const int lane = tid & 63;
    const int wv = tid >> 6;  // 0..3
    const int o4 = lane * 4;

    f32x4 bs[4];
#pragma unroll
    for (int bb = 0; bb < 4; ++bb)
        bs[bb] = *reinterpret_cast<const f32x4*>(&base_s[bb][o4]);

    const int il0 = wv * 32;  // this wave's first i_loc

    // double-buffered sw fragment (28 contiguous floats per lane)
    f32x4 q[7];
    {
        const f32x4* p4 = reinterpret_cast<const f32x4*>(
            &sw[((size_t)(i_base + il0) * NF + o4) * 7]);
#pragma unroll
        for (int m = 0; m < 7; ++m) q[m] = p4[m];
    }

#pragma unroll 2
    for (int t = 0; t < 32; ++t) {
        const int il = il0 + t;
        const int i = i_base + il;

        f32x4 qn[7];
        if (t < 31) {
            const f32x4* p4 = reinterpret_cast<const f32x4*>(
                &sw[((size_t)(i + 1) * NF + o4) * 7]);
#pragma unroll
            for (int m = 0; m < 7; ++m) qn[m] = p4[m];
        }

        // repack q (layout [oo][k], k innermost) into s[oo*7+k]
        float s[28];
#pragma unroll
        for (int m = 0; m < 7; ++m) {
            s[m * 4 + 0] = q[m].x;
            s[m * 4 + 1] = q[m].y;
            s[m * 4 + 2] = q[m].z;
            s[m * 4 + 3] = q[m].w;
        }

#pragma unroll
        for (int bb = 0; bb < 4; ++bb) {
            const f32x4 bl = *reinterpret_cast<const f32x4*>(&bas[bb][il][0]);
            const f32x4 bh = *reinterpret_cast<const f32x4*>(&bas[bb][il][4]);
            const float bk[7] = {bl.x, bl.y, bl.z, bl.w, bh.x, bh.y, bh.z};
            float a0 = bs[bb].x, a1 = bs[bb].y, a2 = bs[bb].z, a3 = bs[bb].w;
#pragma unroll
            for (int k = 0; k < 7; ++k) {
                a0 += bk[k] * s[0 * 7 + k];
                a1 += bk[k] * s[1 * 7 + k];
                a2 += bk[k] * s[2 * 7 + k];
                a3 += bk[k] * s[3 * 7 + k];
            }
            f32x4 ov;
            ov.x = silu_f(a0);
            ov.y = silu_f(a1);
            ov.z = silu_f(a2);
            ov.w = silu_f(a3);
            // stream bb advances +1KB per t -> 32KB contiguous run
            *reinterpret_cast<f32x4*>(
                &out[((size_t)(b0 + bb) * NF + i) * NF + o4]) = ov;
        }

#pragma unroll
        for (int m = 0; m < 7; ++m) q[m] = qn[m];
    }
}

extern "C" void kernel_launch(void* const* d_in, const int* in_sizes, int n_in,
                              void* d_out, int out_size, void* d_ws, size_t ws_size,
                              hipStream_t stream) {
    const float* x    = (const float*)d_in[0];  // (1024, 256)
    const float* bw   = (const float*)d_in[1];  // (256, 256)
    const float* sw   = (const float*)d_in[2];  // (256, 256, 7)
    const float* grid = (const float*)d_in[3];  // (5, 256)
    float* out = (float*)d_out;                 // (1024, 256, 256)
    float* base = (float*)d_ws;                 // 1 MB scratch

    base_gemm<<<dim3(256), 256, 0, stream>>>(x, bw, base);
    kan_main<<<dim3(2, 256), 256, 0, stream>>>(x, sw, grid, base, out);
}

// Round 7
// 87.817 us; speedup vs baseline: 1.0156x; 1.0156x over previous
//
#include <hip/hip_runtime.h>
#include <math.h>

// KANLinear forward, MI355X — single fused kernel, R7.
// out[b,i,o] = silu( (x@W)[b,o] + sum_k basis[b,i,k] * sw[i,o,k] )
// b=1024, i=256, o=256, k=7. Output 268MB f32, write-bound (~39us floor).
// 1024 blocks (4/CU) x 256 thr. Block = 8 b-rows x 32 i. Each block computes
// its own base rows (redundant W reads, L3-served) so no serial gemm dispatch;
// co-resident blocks keep the store stream saturated during prologues.

#define NF 256
#define BR 8   // batch rows per block
#define IW 32  // i-features per block

typedef float f32x4 __attribute__((ext_vector_type(4)));

__device__ __forceinline__ float silu_f(float z) {
    float e = __expf(-z);
    return z * __builtin_amdgcn_rcpf(1.0f + e);
}

__global__ __launch_bounds__(256) void kan_fused(const float* __restrict__ x,
                                                 const float* __restrict__ W,
                                                 const float* __restrict__ sw,
                                                 const float* __restrict__ grid,
                                                 float* __restrict__ out) {
    const int i0 = blockIdx.x * IW;   // 8 i-bands
    const int b0 = blockIdx.y * BR;   // 128 b-chunks
    const int tid = threadIdx.x;

    __shared__ float xs[BR][NF];      // 8 KB
    __shared__ float base_s[BR][NF];  // 8 KB
    __shared__ float bas[BR][IW][8];  // 8 KB

    // ---- Phase 0: load 8 x-rows into LDS (512 f32x4 over 256 threads) ----
#pragma unroll
    for (int r = 0; r < 2; ++r) {
        const int f4 = tid + r * 256;
        const int row = f4 >> 6;
        const int c4 = (f4 & 63) * 4;
        *reinterpret_cast<f32x4*>(&xs[row][c4]) =
            *reinterpret_cast<const f32x4*>(&x[(size_t)(b0 + row) * NF + c4]);
    }
    __syncthreads();

    // ---- Phase 1: base rows = xs @ W (8 x 256) ----
    // thread (oq = tid&63, rp = tid>>6): rows 2rp, 2rp+1; o = oq*4..+3
    {
        const int oq = (tid & 63) * 4;
        const int rp = tid >> 6;
        f32x4 acc0 = {0.f, 0.f, 0.f, 0.f};
        f32x4 acc1 = {0.f, 0.f, 0.f, 0.f};
#pragma unroll 8
        for (int k = 0; k < NF; ++k) {
            const f32x4 w = *reinterpret_cast<const f32x4*>(&W[(size_t)k * NF + oq]);
            const float xa = xs[2 * rp + 0][k];
            const float xb = xs[2 * rp + 1][k];
            acc0 += xa * w;
            acc1 += xb * w;
        }
        *reinterpret_cast<f32x4*>(&base_s[2 * rp + 0][oq]) = acc0;
        *reinterpret_cast<f32x4*>(&base_s[2 * rp + 1][oq]) = acc1;
    }

    // ---- Phase 2: basis for 256 (bb, il) pairs, one per thread ----
    {
        const int il = tid & (IW - 1);
        const int bb = tid >> 5;
        const int i = i0 + il;
        const float g0 = grid[0 * NF + i];
        const float g1 = grid[1 * NF + i];
        const float g2 = grid[2 * NF + i];
        const float g3 = grid[3 * NF + i];
        const float g4 = grid[4 * NF + i];
        const float L = 2.f * g0 - g3;
        const float R = 2.f * g4 - g1;
        const float eg[11] = {L, L, L, g0, g1, g2, g3, g4, R, R, R};
        const float xv = xs[bb][i];

        float B0[10];
#pragma unroll
        for (int t = 0; t < 10; ++t)
            B0[t] = (xv >= eg[t] && xv < eg[t + 1]) ? 1.f : 0.f;
        float B1[9];
#pragma unroll
        for (int t = 0; t < 9; ++t) {
            const float dl = eg[t + 1] - eg[t];
            const float dr = eg[t + 2] - eg[t + 1];
            const float lt = (dl != 0.f) ? (xv - eg[t]) / dl : 0.f;
            const float rt = (dr != 0.f) ? (eg[t + 2] - xv) / dr : 0.f;
            B1[t] = lt * B0[t] + rt * B0[t + 1];
        }
        float B2[8];
#pragma unroll
        for (int t = 0; t < 8; ++t) {
            const float dl = eg[t + 2] - eg[t];
            const float dr = eg[t + 3] - eg[t + 1];
            const float lt = (dl != 0.f) ? (xv - eg[t]) / dl : 0.f;
            const float rt = (dr != 0.f) ? (eg[t + 3] - xv) / dr : 0.f;
            B2[t] = lt * B1[t] + rt * B1[t + 1];
        }
#pragma unroll
        for (int k = 0; k < 7; ++k) bas[bb][il][k] = B2[k];
        bas[bb][il][7] = 0.f;
    }
    __syncthreads();

    // ---- Phase 3: main loop (identical inner structure to R4 winner) ----
    const int lane = tid & 63;
    const int wv = tid >> 6;
    const int o4 = lane * 4;

    for (int step = 0; step < IW / 4; ++step) {  // 8 steps
        const int il = step * 4 + wv;            // consecutive waves -> adjacent i
        const int i = i0 + il;

        // sw fragment: 28 contiguous floats per lane = 7 x dwordx4
        f32x4 q[7];
        const f32x4* p4 = reinterpret_cast<const f32x4*>(
            &sw[((size_t)i * NF + o4) * 7]);
#pragma unroll
        for (int j = 0; j < 7; ++j) q[j] = p4[j];
        float s[28];
#pragma unroll
        for (int j = 0; j < 7; ++j) {
            s[j * 4 + 0] = q[j].x; s[j * 4 + 1] = q[j].y;
            s[j * 4 + 2] = q[j].z; s[j * 4 + 3] = q[j].w;
        }

        float* op = out + ((size_t)b0 * NF + i) * NF + o4;

#pragma unroll
        for (int bb = 0; bb < BR; ++bb) {
            const f32x4 bl = *reinterpret_cast<const f32x4*>(&bas[bb][il][0]);
            const f32x4 bh = *reinterpret_cast<const f32x4*>(&bas[bb][il][4]);
            const float bk[7] = {bl.x, bl.y, bl.z, bl.w, bh.x, bh.y, bh.z};
            const f32x4 bs = *reinterpret_cast<const f32x4*>(&base_s[bb][o4]);
            float a0 = bs.x, a1 = bs.y, a2 = bs.z, a3 = bs.w;
#pragma unroll
            for (int k = 0; k < 7; ++k) {
                a0 += bk[k] * s[0 * 7 + k];
                a1 += bk[k] * s[1 * 7 + k];
                a2 += bk[k] * s[2 * 7 + k];
                a3 += bk[k] * s[3 * 7 + k];
            }
            f32x4 ov;
            ov.x = silu_f(a0);
            ov.y = silu_f(a1);
            ov.z = silu_f(a2);
            ov.w = silu_f(a3);
            *reinterpret_cast<f32x4*>(op + (size_t)bb * NF * NF) = ov;
        }
    }
}

extern "C" void kernel_launch(void* const* d_in, const int* in_sizes, int n_in,
                              void* d_out, int out_size, void* d_ws, size_t ws_size,
                              hipStream_t stream) {
    const float* x    = (const float*)d_in[0];  // (1024, 256)
    const float* bw   = (const float*)d_in[1];  // (256, 256)
    const float* sw   = (const float*)d_in[2];  // (256, 256, 7)
    const float* grid = (const float*)d_in[3];  // (5, 256)
    float* out = (float*)d_out;                 // (1024, 256, 256)

    kan_fused<<<dim3(NF / IW, 1024 / BR), 256, 0, stream>>>(x, bw, sw, grid, out);
}